// Round 2
// baseline (426.841 us; speedup 1.0000x reference)
//
#include <hip/hip_runtime.h>
#include <math.h>

#define WIN   400
#define NREF  64
#define KTOP  8
#define NSNP  400000
#define NB    2
#define NA    3
#define NW    1000        // NSNP / WIN
#define WT    10          // windows per phase-1 block
#define NWT   (NW / WT)   // 100 window-tiles
#define TILE_F4 (WT * WIN / 4)  // 1000 float4 per stream per block

// ---------------- Phase 1: windowed means, pure streaming ----------------
// One block per (a, r, wtile). Stage ref tile + both mixed tiles in LDS with
// unit-stride float4 loads; compute per-window partials with stride-25 f4
// reads (<=2-way bank aliasing == free); reduce 25 partials per (window,b).
__global__ __launch_bounds__(256) void win_mean_kernel(
    const float* __restrict__ mixed,   // [NB, NSNP]
    const float* __restrict__ ref,     // [NA, NREF, NSNP]
    float* __restrict__ wmean)         // [NB, NA, NW, NREF]
{
    __shared__ float4 sref[TILE_F4];   // 16 KB
    __shared__ float4 smx0[TILE_F4];   // 16 KB
    __shared__ float4 smx1[TILE_F4];   // 16 KB
    __shared__ float  part0[256];      // 1 KB
    __shared__ float  part1[256];      // 1 KB

    const int bid = blockIdx.x;
    const int a   = bid / (NREF * NWT);
    const int rem = bid % (NREF * NWT);
    const int r   = rem / NWT;
    const int wt  = rem % NWT;
    const int t   = threadIdx.x;

    const float4* gref = reinterpret_cast<const float4*>(
        ref + (size_t)(a * NREF + r) * NSNP + (size_t)wt * WT * WIN);
    const float4* gm0 = reinterpret_cast<const float4*>(
        mixed + (size_t)wt * WT * WIN);
    const float4* gm1 = reinterpret_cast<const float4*>(
        mixed + (size_t)NSNP + (size_t)wt * WT * WIN);

    #pragma unroll
    for (int j = 0; j < 4; ++j) {
        const int idx = t + 256 * j;
        if (idx < TILE_F4) {
            sref[idx] = gref[idx];
            smx0[idx] = gm0[idx];
            smx1[idx] = gm1[idx];
        }
    }
    __syncthreads();

    if (t < WT * 25) {                 // 250 active: (window, 16-float segment)
        const int wloc = t / 25;
        const int s    = t % 25;
        float acc0 = 0.0f, acc1 = 0.0f;
        #pragma unroll
        for (int i = 0; i < 4; ++i) {
            const int f = wloc * 100 + s + 25 * i;   // window's 100 f4, stride 25
            const float4 rv = sref[f];
            const float4 m0 = smx0[f];
            const float4 m1 = smx1[f];
            acc0 += rv.x * m0.x + rv.y * m0.y + rv.z * m0.z + rv.w * m0.w;
            acc1 += rv.x * m1.x + rv.y * m1.y + rv.z * m1.z + rv.w * m1.w;
        }
        part0[t] = acc0;
        part1[t] = acc1;
    }
    __syncthreads();

    if (t < 2 * WT) {                  // 20 threads: (window, batch)
        const int b    = t & 1;
        const int wloc = t >> 1;
        const float* p = b ? part1 : part0;
        float s = 0.0f;
        #pragma unroll
        for (int i = 0; i < 25; ++i) s += p[wloc * 25 + i];
        const int w = wt * WT + wloc;
        wmean[(((size_t)b * NA + a) * NW + w) * NREF + r] = s * (1.0f / WIN);
    }
}

// ---------------- Phase 2: top-8 over 64 refs + weighted sum ----------------
// One wave per (b, a, w) group; lane = ref index. jax.lax.top_k semantics:
// descending values, ties -> lower index (validated in round 1, absmax 0).
__global__ __launch_bounds__(256) void topk_kernel(
    const float* __restrict__ wmean,    // [NB*NA*NW, NREF]
    const float* __restrict__ weights,  // [KTOP, 1]
    float* __restrict__ out)            // [NB*NA*NW] then [NB*NA*NW*KTOP] idx
{
    const int lane = threadIdx.x & 63;
    const int wave = threadIdx.x >> 6;
    const int g    = blockIdx.x * 4 + wave;   // (b*NA + a)*NW + w
    if (g >= NB * NA * NW) return;

    float myval = wmean[(size_t)g * NREF + lane];
    float wsum  = 0.0f;
    float idxs[KTOP];
    #pragma unroll
    for (int k = 0; k < KTOP; ++k) {
        float v = myval;
        int   i = lane;
        #pragma unroll
        for (int off = 32; off > 0; off >>= 1) {
            float v2 = __shfl_xor(v, off, 64);
            int   i2 = __shfl_xor(i, off, 64);
            if (v2 > v || (v2 == v && i2 < i)) { v = v2; i = i2; }
        }
        wsum   += weights[k] * v;
        idxs[k] = (float)i;
        if (lane == i) myval = -INFINITY;
    }
    if (lane == 0) {
        out[g] = wsum;
        float4* op = reinterpret_cast<float4*>(
            out + (size_t)NB * NA * NW + (size_t)g * KTOP);
        op[0] = make_float4(idxs[0], idxs[1], idxs[2], idxs[3]);
        op[1] = make_float4(idxs[4], idxs[5], idxs[6], idxs[7]);
    }
}

extern "C" void kernel_launch(void* const* d_in, const int* in_sizes, int n_in,
                              void* d_out, int out_size, void* d_ws, size_t ws_size,
                              hipStream_t stream) {
    const float* mixed   = (const float*)d_in[0];
    const float* ref     = (const float*)d_in[1];
    const float* weights = (const float*)d_in[2];
    float* out   = (float*)d_out;
    float* wmean = (float*)d_ws;   // NB*NA*NW*NREF = 384000 floats = 1.5 MB

    win_mean_kernel<<<NA * NREF * NWT, 256, 0, stream>>>(mixed, ref, wmean);
    topk_kernel<<<(NB * NA * NW + 3) / 4, 256, 0, stream>>>(wmean, weights, out);
}

// Round 3
// 414.358 us; speedup vs baseline: 1.0301x; 1.0301x over previous
//
#include <hip/hip_runtime.h>
#include <math.h>

#define WIN   400
#define NREF  64
#define KTOP  8
#define NSNP  400000
#define NB    2
#define NA    3
#define NW    1000
#define HF4   50            // float4 per half-window row (200 floats)

// Async global->LDS DMA, 16 B per active lane. LDS dest = wave-uniform base +
// lane*16 (m104/m108 semantics); our layout is exactly lane-contiguous.
__device__ __forceinline__ void async_copy16(void* lds, const void* g) {
    __builtin_amdgcn_global_load_lds(
        (const __attribute__((address_space(1))) unsigned int*)g,
        (__attribute__((address_space(3))) unsigned int*)lds,
        16, 0, 0);
}

// One block per (a, w). Stage 64 x half-window via global_load_lds (16 DMA
// instrs/wave in flight = 12.8 KB/wave outstanding -> HBM latency fully
// covered without VGPR cost). 2 blocks/CU (56.4 KB LDS) so one block's
// compute overlaps the other's staging. Fused top-k (round-1 validated).
__global__ __launch_bounds__(256, 2) void fused_kernel(
    const float* __restrict__ mixed,    // [NB, NSNP]
    const float* __restrict__ ref,      // [NA, NREF, NSNP]
    const float* __restrict__ weights,  // [KTOP, 1]
    float* __restrict__ out)            // [6000] vals, then [6000*8] idx-as-f32
{
    __shared__ float4 sref[NREF * HF4];   // 51.2 KB: [r][50] f4, half-window
    __shared__ float4 smix[2 * 100];      // 3.2 KB: full window, both b
    __shared__ float  part[NB][4][NREF];  // 2 KB

    const int bid  = blockIdx.x;
    const int a    = bid / NW;
    const int w    = bid % NW;
    const int t    = threadIdx.x;
    const int lane = t & 63;
    const int wv   = t >> 6;

    // compute-phase mapping: r = lane, seg = wave; seg f4-ranges within the
    // half: starts {0,13,26,38}, lens {13,13,12,12}
    const int r   = lane;
    const int seg = wv;
    const int st  = seg * 13 - (seg == 3 ? 1 : 0);
    const int len = (seg < 2) ? 13 : 12;

    float acc0 = 0.0f, acc1 = 0.0f;

    for (int h = 0; h < 2; ++h) {
        // ---- stage ref rows [wv*16, wv*16+16), half h: one DMA per row ----
        const float* gbase = ref + (size_t)(a * NREF + wv * 16) * NSNP
                                 + (size_t)w * WIN + h * (WIN / 2);
        #pragma unroll
        for (int j = 0; j < 16; ++j) {
            const float4* g =
                reinterpret_cast<const float4*>(gbase + (size_t)j * NSNP) + lane;
            if (lane < HF4)
                async_copy16(&sref[(wv * 16 + j) * HF4], g);
        }
        // ---- stage mixed (full window, both b) once, waves 0/1 ----
        if (h == 0 && wv < NB) {
            const float4* gm = reinterpret_cast<const float4*>(
                mixed + (size_t)wv * NSNP + (size_t)w * WIN);
            async_copy16(&smix[wv * 100], gm + lane);
            if (lane < 36)
                async_copy16(&smix[wv * 100 + 64], gm + 64 + lane);
        }
        __syncthreads();   // barrier drains vmcnt -> all DMAs landed

        // ---- partial dots: thread (r, seg) owns its f4 range, both b ----
        const float4* rp = &sref[r * HF4 + st];
        const float4* m0 = &smix[0 * 100 + h * HF4 + st];
        const float4* m1 = &smix[1 * 100 + h * HF4 + st];
        for (int i = 0; i < len; ++i) {
            const float4 rv = rp[i];
            const float4 x0 = m0[i];   // broadcast (all lanes same addr)
            const float4 x1 = m1[i];
            acc0 += rv.x * x0.x + rv.y * x0.y + rv.z * x0.z + rv.w * x0.w;
            acc1 += rv.x * x1.x + rv.y * x1.y + rv.z * x1.z + rv.w * x1.w;
        }
        __syncthreads();   // h=1 staging must not overwrite live sref
    }

    part[0][seg][r] = acc0;
    part[1][seg][r] = acc1;
    __syncthreads();

    // ---- top-8 over 64 refs + weighted sum (round-1 validated semantics) ----
    if (wv < NB) {
        const int b = wv;
        float myval = (part[b][0][lane] + part[b][1][lane] +
                       part[b][2][lane] + part[b][3][lane]) * (1.0f / WIN);
        float wsum  = 0.0f;
        float idxs[KTOP];
        #pragma unroll
        for (int k = 0; k < KTOP; ++k) {
            float v = myval;
            int   i = lane;
            #pragma unroll
            for (int off = 32; off > 0; off >>= 1) {
                float v2 = __shfl_xor(v, off, 64);
                int   i2 = __shfl_xor(i, off, 64);
                if (v2 > v || (v2 == v && i2 < i)) { v = v2; i = i2; }
            }
            wsum   += weights[k] * v;
            idxs[k] = (float)i;
            if (lane == i) myval = -INFINITY;
        }
        if (lane == 0) {
            const int g = (b * NA + a) * NW + w;
            out[g] = wsum;
            float4* op = reinterpret_cast<float4*>(
                out + (size_t)NB * NA * NW + (size_t)g * KTOP);
            op[0] = make_float4(idxs[0], idxs[1], idxs[2], idxs[3]);
            op[1] = make_float4(idxs[4], idxs[5], idxs[6], idxs[7]);
        }
    }
}

extern "C" void kernel_launch(void* const* d_in, const int* in_sizes, int n_in,
                              void* d_out, int out_size, void* d_ws, size_t ws_size,
                              hipStream_t stream) {
    const float* mixed   = (const float*)d_in[0];
    const float* ref     = (const float*)d_in[1];
    const float* weights = (const float*)d_in[2];
    float* out = (float*)d_out;
    fused_kernel<<<NA * NW, 256, 0, stream>>>(mixed, ref, weights, out);
}